// Round 2
// baseline (118.670 us; speedup 1.0000x reference)
//
#include <hip/hip_runtime.h>

#define NIMG 4
#define NCLS 19
#define CCH  32
#define LH   128
#define LW   128
#define HH   512
#define WW   512
#define HWQ  (LH*LW)    // 16384 low-res pixels
#define HWP  (HH*WW)    // 262144 hi-res pixels

// k_field tiling: each block OWNS a disjoint TRxTC low-res region
#define TR 8
#define TC 16
#define NTX (LW/TC)       // 8
#define NTY (LH/TR)       // 16
#define NTILE (NTY*NTX)   // 128 blocks per image
#define TCELLS (TR*TC)    // 128

#define PRR 11            // E-patch rows  (Y0-1 .. Y0+9, clamped)
#define PCC 19            // E-patch cols  (X0-1 .. X0+17, clamped)
#define PSTR (PRR*PCC)    // 209 floats per channel (odd -> bank-friendly)

// Bilinear taps for 128 -> 512, half-pixel convention. Edge taps shifted to a
// valid (b, b+1) pair with weights {1,0}/{0,1} (exact dyadic, same math).
__device__ __forceinline__ void taps(int v, int lim, int& i0, float& w0, float& w1) {
    int r = v & 3;
    int b = (v >> 2) + ((r < 2) ? -1 : 0);
    float f = 0.125f + 0.25f * (float)((r + 2) & 3);   // r: 0->.625 1->.875 2->.125 3->.375
    w0 = 1.f - f; w1 = f;
    if (b < 0)           { b = 0;       w0 = 1.f; w1 = 0.f; }
    else if (b >= lim)   { b = lim - 1; w0 = 0.f; w1 = 1.f; }
    i0 = b;
}

// K1 (fused): E-patch -> LDS, Gram ring in-LDS, quad-row halo pass (A-field +
// per-pixel S2 via Gram), contract via LDS float atomics.
//   P_sum[n][tile][k][c] = sum_{cells} A[k][cell] * E[c][cell]
//   P_cnt[n][tile][k]    = sum_{cells} A[k][cell]
//   P_S2 [n][tile][k]    = sum_{owned pixels of class k} ||v_p||^2
__global__ __launch_bounds__(256) void k_field(const float* __restrict__ E,
        const int* __restrict__ lab,
        float* __restrict__ P_sum, float* __restrict__ P_cnt, float* __restrict__ P_S2) {
    int tile = blockIdx.x, n = blockIdx.y;
    int ty = tile >> 3, tx = tile & 7;          // NTX=8
    int Y0 = ty * TR, X0 = tx * TC;
    __shared__ float Ep[CCH * PSTR];            // 26.75 KB  [ch][r*19+c]
    __shared__ float A[TCELLS * NCLS];          // 9.73 KB   [cell][k]
    __shared__ float Gt[4 * 180];               // 2.88 KB   Gs,Gh,Gv,Gda ring (10x18)
    __shared__ float cs[NCLS * CCH];            // 2.43 KB   contract accumulator
    __shared__ float S2w[4 * NCLS];             // per-wave S2 accumulators
    __shared__ float tmpc[NCLS * 8];            // cnt partials
    int tid = threadIdx.x;

    // ---- P1: zero + stage E patch (clamped coords; rows/cols beyond image edge
    // replicate the border, matching plane evaluation at clamped cells) ----
    for (int i = tid; i < TCELLS * NCLS; i += 256) A[i] = 0.f;
    for (int i = tid; i < NCLS * CCH; i += 256) cs[i] = 0.f;
    if (tid < 4 * NCLS) S2w[tid] = 0.f;
    const float* En = E + (size_t)n * CCH * HWQ;
    for (int i = tid; i < CCH * PSTR; i += 256) {
        int ch = i / PSTR, rem = i - ch * PSTR;
        int r = rem / PCC, c = rem - r * PCC;
        int yy = Y0 - 1 + r; yy = yy < 0 ? 0 : (yy > LH - 1 ? LH - 1 : yy);
        int xx = X0 - 1 + c; xx = xx < 0 ? 0 : (xx > LW - 1 ? LW - 1 : xx);
        Ep[i] = En[ch * HWQ + yy * LW + xx];
    }
    __syncthreads();

    // ---- P2: Gram ring, 180 cells x {self, h, v, diag+anti} over 32 ch ----
    if (tid < 180) {
        int gy = tid / 18, gx = tid - gy * 18;
        int yi = Y0 - 1 + gy; yi = yi < 0 ? 0 : (yi > LH - 1 ? LH - 1 : yi);
        int xi = X0 - 1 + gx; xi = xi < 0 ? 0 : (xi > LW - 1 ? LW - 1 : xi);
        int yn = (yi + 1 > LH - 1) ? LH - 1 : yi + 1;
        int xn = (xi + 1 > LW - 1) ? LW - 1 : xi + 1;
        int p00 = (yi - Y0 + 1) * PCC + (xi - X0 + 1);
        int p01 = (yi - Y0 + 1) * PCC + (xn - X0 + 1);
        int p10 = (yn - Y0 + 1) * PCC + (xi - X0 + 1);
        int p11 = (yn - Y0 + 1) * PCC + (xn - X0 + 1);
        float gs = 0.f, gh = 0.f, gv = 0.f, gda = 0.f;
        const float* ep = Ep;
#pragma unroll 8
        for (int ch = 0; ch < CCH; ch++, ep += PSTR) {
            float a = ep[p00], ar = ep[p01], b = ep[p10], br = ep[p11];
            gs = fmaf(a, a, gs);
            gh = fmaf(a, ar, gh);
            gv = fmaf(a, b, gv);
            gda = fmaf(a, br, fmaf(ar, b, gda));
        }
        Gt[tid] = gs; Gt[180 + tid] = gh; Gt[360 + tid] = gv; Gt[540 + tid] = gda;
    }
    __syncthreads();

    // ---- P3: halo pass, one thread per 4-pixel quad-row ----
    const float* Gs_ = Gt, * Gh_ = Gt + 180, * Gv_ = Gt + 360, * Gda_ = Gt + 540;
    const int* ln = lab + (size_t)n * HWP;
    int h_lo = Y0 * 4 - 2;
    for (int i = tid; i < 36 * 18; i += 256) {
        int hr = i / 18, qi = i - hr * 18;
        int h = h_lo + hr;
        int q = X0 - 1 + qi;                 // quad column (4 hi-res pixels)
        if (h < 0 || h >= HH || q < 0 || q >= LW) continue;
        int y0; float wy0, wy1;
        taps(h, LH - 1, y0, wy0, wy1);
        int ry = y0 - Y0;
        bool r0 = (unsigned)ry < (unsigned)TR, r1 = (unsigned)(ry + 1) < (unsigned)TR;
        int rxm = q - 1 - X0, rx0 = q - X0, rxp = q + 1 - X0;
        bool bm = (unsigned)rxm < (unsigned)TC, b0 = (unsigned)rx0 < (unsigned)TC,
             bp = (unsigned)rxp < (unsigned)TC;
        int4 l4 = *(const int4*)(ln + h * WW + (q << 2));
        bool fast = (q >= 1) && (q <= 126);
        bool owned = ((unsigned)(h - Y0 * 4) < 32u) && b0;

        if (fast) {
            // x-weights fixed: p0:(q-1:.375,q:.625) p1:(.125,.875) p2:(q:.875,q+1:.125) p3:(.625,.375)
            if (r0) {
                int rb = (ry * TC) * NCLS;
                if (bm) { float* a = &A[rb + rxm * NCLS];
                    atomicAdd(a + l4.x, wy0 * 0.375f); atomicAdd(a + l4.y, wy0 * 0.125f); }
                if (b0) { float* a = &A[rb + rx0 * NCLS];
                    atomicAdd(a + l4.x, wy0 * 0.625f); atomicAdd(a + l4.y, wy0 * 0.875f);
                    atomicAdd(a + l4.z, wy0 * 0.875f); atomicAdd(a + l4.w, wy0 * 0.625f); }
                if (bp) { float* a = &A[rb + rxp * NCLS];
                    atomicAdd(a + l4.z, wy0 * 0.125f); atomicAdd(a + l4.w, wy0 * 0.375f); }
            }
            if (r1) {
                int rb = ((ry + 1) * TC) * NCLS;
                if (bm) { float* a = &A[rb + rxm * NCLS];
                    atomicAdd(a + l4.x, wy1 * 0.375f); atomicAdd(a + l4.y, wy1 * 0.125f); }
                if (b0) { float* a = &A[rb + rx0 * NCLS];
                    atomicAdd(a + l4.x, wy1 * 0.625f); atomicAdd(a + l4.y, wy1 * 0.875f);
                    atomicAdd(a + l4.z, wy1 * 0.875f); atomicAdd(a + l4.w, wy1 * 0.625f); }
                if (bp) { float* a = &A[rb + rxp * NCLS];
                    atomicAdd(a + l4.z, wy1 * 0.125f); atomicAdd(a + l4.w, wy1 * 0.375f); }
            }
            if (owned) {
                // d2 = s0*C(x0) + s1*C(x0+1) + s2*D(x0); shared C/D across the quad
                float u0 = wy0 * wy0, u1 = wy1 * wy1, u2t = 2.f * wy0 * wy1;
                int g00 = (y0 - Y0 + 1) * 18 + rx0;      // ring col of x=q-1
                float C0 = u0 * Gs_[g00]     + u1 * Gs_[g00 + 18] + u2t * Gv_[g00];
                float C1 = u0 * Gs_[g00 + 1] + u1 * Gs_[g00 + 19] + u2t * Gv_[g00 + 1];
                float C2 = u0 * Gs_[g00 + 2] + u1 * Gs_[g00 + 20] + u2t * Gv_[g00 + 2];
                float D0 = 2.f * (u0 * Gh_[g00]     + u1 * Gh_[g00 + 18]) + u2t * Gda_[g00];
                float D1 = 2.f * (u0 * Gh_[g00 + 1] + u1 * Gh_[g00 + 19]) + u2t * Gda_[g00 + 1];
                float d2a = fmaf(0.140625f, C0, fmaf(0.390625f, C1, 0.46875f * D0));
                float d2b = fmaf(0.015625f, C0, fmaf(0.765625f, C1, 0.21875f * D0));
                float d2c = fmaf(0.765625f, C1, fmaf(0.015625f, C2, 0.21875f * D1));
                float d2d = fmaf(0.390625f, C1, fmaf(0.140625f, C2, 0.46875f * D1));
                int wv = (tid >> 6) * NCLS;
                atomicAdd(&S2w[wv + l4.x], d2a); atomicAdd(&S2w[wv + l4.y], d2b);
                atomicAdd(&S2w[wv + l4.z], d2c); atomicAdd(&S2w[wv + l4.w], d2d);
            }
        } else {
            // image-border quads: per-pixel taps (clamp-shifted weights)
            int Ls[4] = {l4.x, l4.y, l4.z, l4.w};
            float u0 = wy0 * wy0, u1 = wy1 * wy1, u2t = 2.f * wy0 * wy1;
            int gyr = y0 - Y0 + 1;
            int wv = (tid >> 6) * NCLS;
#pragma unroll
            for (int j = 0; j < 4; j++) {
                int w = (q << 2) + j;
                int x0; float wx0, wx1;
                taps(w, LW - 1, x0, wx0, wx1);
                int rxa = x0 - X0, rxb = rxa + 1;
                int L = Ls[j];
                if (r0) {
                    int rb = (ry * TC) * NCLS;
                    if ((unsigned)rxa < (unsigned)TC) atomicAdd(&A[rb + rxa * NCLS + L], wy0 * wx0);
                    if ((unsigned)rxb < (unsigned)TC) atomicAdd(&A[rb + rxb * NCLS + L], wy0 * wx1);
                }
                if (r1) {
                    int rb = ((ry + 1) * TC) * NCLS;
                    if ((unsigned)rxa < (unsigned)TC) atomicAdd(&A[rb + rxa * NCLS + L], wy1 * wx0);
                    if ((unsigned)rxb < (unsigned)TC) atomicAdd(&A[rb + rxb * NCLS + L], wy1 * wx1);
                }
                if (owned) {
                    int gg = gyr * 18 + (x0 - X0 + 1);
                    float Ca = u0 * Gs_[gg]     + u1 * Gs_[gg + 18] + u2t * Gv_[gg];
                    float Cb = u0 * Gs_[gg + 1] + u1 * Gs_[gg + 19] + u2t * Gv_[gg + 1];
                    float Dd = 2.f * (u0 * Gh_[gg] + u1 * Gh_[gg + 18]) + u2t * Gda_[gg];
                    float d2 = wx0 * wx0 * Ca + wx1 * wx1 * Cb + 2.f * wx0 * wx1 * Dd;
                    atomicAdd(&S2w[wv + L], d2);
                }
            }
        }
    }
    __syncthreads();

    // ---- P4: contract (A * E over owned cells) via per-thread acc + LDS ds_add;
    //          cnt partials; S2 finalize ----
    {
        int g = tid >> 5, c = tid & 31;
        float acc[NCLS];
#pragma unroll
        for (int k = 0; k < NCLS; k++) acc[k] = 0.f;
        const float* epc = Ep + c * PSTR;
#pragma unroll
        for (int j = 0; j < TCELLS / 8; j++) {
            int cell = g * (TCELLS / 8) + j;
            int cy = cell >> 4, cx = cell & 15;
            float e = epc[(cy + 1) * PCC + (cx + 1)];
            const float* Ar = &A[cell * NCLS];
#pragma unroll
            for (int k = 0; k < NCLS; k++) acc[k] = fmaf(Ar[k], e, acc[k]);
        }
#pragma unroll
        for (int k = 0; k < NCLS; k++) atomicAdd(&cs[k * CCH + c], acc[k]);
    }
    if (tid < 152) {                          // 8 groups x 19 classes, 16 cells each
        int g8 = tid / NCLS, k = tid - g8 * NCLS;
        float s = 0.f;
        const float* Ac = A + g8 * 16 * NCLS + k;
#pragma unroll
        for (int j = 0; j < 16; j++) s += Ac[j * NCLS];
        tmpc[k * 8 + g8] = s;
    }
    if (tid < NCLS) {
        P_S2[(size_t)(n * NTILE + tile) * NCLS + tid] =
            S2w[tid] + S2w[NCLS + tid] + S2w[2 * NCLS + tid] + S2w[3 * NCLS + tid];
    }
    __syncthreads();

    // ---- P5: write partials ----
    float* Ps = P_sum + (size_t)(n * NTILE + tile) * (NCLS * CCH);
    for (int idx = tid; idx < NCLS * CCH; idx += 256) Ps[idx] = cs[idx];
    if (tid < NCLS) {
        float s = 0.f;
#pragma unroll
        for (int g8 = 0; g8 < 8; g8++) s += tmpc[tid * 8 + g8];
        P_cnt[(size_t)(n * NTILE + tile) * NCLS + tid] = s;
    }
}

// K3: reduce partials, intra via S2 - 2 m.s + cnt |m|^2, inter pairwise, output
__global__ __launch_bounds__(384) void k_final(const float* __restrict__ P_sum,
        const float* __restrict__ P_cnt, const float* __restrict__ P_S2,
        float* __restrict__ out) {
    int n = blockIdx.x, t = threadIdx.x;
    __shared__ float csum[NCLS * 33];   // stride-33 pad
    __shared__ float m[NCLS * 33];
    __shared__ float cnt[NCLS];
    __shared__ float S2[NCLS];
    __shared__ float rk1[NCLS * 17];
    __shared__ float rk2[NCLS * 17];
    __shared__ float4 p4buf[304];
    __shared__ float sIntra, sNfg, sInter;

    if (t == 0) sInter = 0.f;
    if (t < 304) {                       // cnt/S2: 19 classes x 16 groups, 8 tiles each
        int k = t >> 4, gg = t & 15;
        const float* p1 = P_cnt + ((size_t)n * NTILE + gg * 8) * NCLS + k;
        const float* p2 = P_S2  + ((size_t)n * NTILE + gg * 8) * NCLS + k;
        float s1 = 0.f, s2 = 0.f;
#pragma unroll
        for (int j = 0; j < 8; j++) { s1 += p1[j * NCLS]; s2 += p2[j * NCLS]; }
        rk1[k * 17 + gg] = s1; rk2[k * 17 + gg] = s2;
    }
    if (t < 304) {                       // P_sum: 152 float4 x 2 tile-halves
        int bg = t / 152, i4 = t - bg * 152;
        const float4* p4 = (const float4*)P_sum + (size_t)n * NTILE * 152 + i4;
        float4 s = make_float4(0.f, 0.f, 0.f, 0.f);
        for (int b = bg * 64; b < bg * 64 + 64; b++) {
            float4 v = p4[(size_t)b * 152];
            s.x += v.x; s.y += v.y; s.z += v.z; s.w += v.w;
        }
        p4buf[t] = s;
    }
    __syncthreads();
    if (t < 152) {
        float4 a = p4buf[t], b = p4buf[152 + t];
        int k = t >> 3, c0 = (t & 7) * 4;
        csum[k * 33 + c0]     = a.x + b.x;
        csum[k * 33 + c0 + 1] = a.y + b.y;
        csum[k * 33 + c0 + 2] = a.z + b.z;
        csum[k * 33 + c0 + 3] = a.w + b.w;
    }
    if (t < NCLS) {
        float s1 = 0.f, s2 = 0.f;
        for (int gg = 0; gg < 16; gg++) { s1 += rk1[t * 17 + gg]; s2 += rk2[t * 17 + gg]; }
        cnt[t] = s1; S2[t] = s2;
    }
    __syncthreads();
    for (int idx = t; idx < NCLS * CCH; idx += 384) {
        int k = idx >> 5, c = idx & 31;
        m[k * 33 + c] = csum[k * 33 + c] / (cnt[k] + 1.f);
    }
    __syncthreads();

    // intra + n_fg (all of t<19 sits in wave 0)
    float vi = 0.f, fg = 0.f;
    if (t >= 1 && t < NCLS && cnt[t] > 0.f) {
        fg = 1.f;
        float dot = 0.f, mm = 0.f;
        for (int c = 0; c < CCH; c++) {
            float mv = m[t * 33 + c];
            dot = fmaf(mv, csum[t * 33 + c], dot);
            mm = fmaf(mv, mv, mm);
        }
        vi = (S2[t] - 2.f * dot + cnt[t] * mm) * (1.f / 32.f) / (cnt[t] + 1.f);
    }
#pragma unroll
    for (int s_ = 32; s_ >= 1; s_ >>= 1) { vi += __shfl_xor(vi, s_); fg += __shfl_xor(fg, s_); }
    if (t == 0) { sIntra = vi; sNfg = fg; }

    // inter: 18x18 foreground pairs
    float ve = 0.f;
    if (t < 324) {
        int j = 1 + t / 18, k = 1 + t % 18;
        if (cnt[j] > 0.f && cnt[k] > 0.f) {
            float s = 0.f;
            for (int c = 0; c < CCH; c++) {
                float d = m[j * 33 + c] - m[k * 33 + c];
                s = fmaf(d, d, s);
            }
            ve = s * (1.f / 32.f);
        }
    }
#pragma unroll
    for (int s_ = 32; s_ >= 1; s_ >>= 1) ve += __shfl_xor(ve, s_);
    if ((t & 63) == 0) atomicAdd(&sInter, ve);
    __syncthreads();
    if (t == 0) out[n] = sIntra / sNfg - sInter / (sNfg * sNfg);
}

extern "C" void kernel_launch(void* const* d_in, const int* in_sizes, int n_in,
                              void* d_out, int out_size, void* d_ws, size_t ws_size,
                              hipStream_t stream) {
    const float* E = (const float*)d_in[0];   // (4,32,128,128) fp32
    const int* lab = (const int*)d_in[1];     // (4,512,512) int
    float* out = (float*)d_out;               // (4,) fp32

    float* ws = (float*)d_ws;
    float* P_sum = ws;                                        // 4*128*608
    float* P_cnt = P_sum + (size_t)NIMG * NTILE * NCLS * CCH; // 4*128*19
    float* P_S2  = P_cnt + (size_t)NIMG * NTILE * NCLS;       // 4*128*19
    // all slots fully overwritten every call -> no memset needed

    k_field<<<dim3(NTILE, NIMG), dim3(256), 0, stream>>>(E, lab, P_sum, P_cnt, P_S2);
    k_final<<<dim3(NIMG),        dim3(384), 0, stream>>>(P_sum, P_cnt, P_S2, out);
}